// Round 1
// baseline (1173.911 us; speedup 1.0000x reference)
//
#include <hip/hip_runtime.h>
#include <math.h>

#define T_ 32
#define P_ 14
#define H_ 12
#define D_ 64
#define L_ 196
#define DM_ 768
#define S_ 16

// ---------------- Kernel A: temporal path, one wg per (b, l) ----------------
// gram(32x32 over D=64) per 24 channels -> row softmax -> 3x3 conv (24ch -> 1)
// -> LayerNorm(1024) -> MLP 1024->32->1024 (exact GELU) -> residual -> affbuf
__global__ __launch_bounds__(256)
void temporal_kernel(const float* __restrict__ q, const float* __restrict__ k,
                     const float* __restrict__ tw, const float* __restrict__ tbias,
                     const float* __restrict__ lng, const float* __restrict__ lnb,
                     const float* __restrict__ w1, const float* __restrict__ b1,
                     const float* __restrict__ w2, const float* __restrict__ b2,
                     float* __restrict__ affbuf)
{
    const int l = blockIdx.x;   // 0..195
    const int b = blockIdx.y;   // 0..15
    const int tid = threadIdx.x;

    __shared__ float Xs[T_ * 64];   // 32x64 tile, XOR-swizzled within rows
    __shared__ float As[T_ * 37];   // 32x32 plane, pitch 37 (bank spread)
    __shared__ float nls[1024];     // LN output
    __shared__ float scratch[256];  // MLP1 partials
    __shared__ float h1s[32];
    __shared__ float redv[8];

    // conv / output-pixel mapping: thread owns row pi, cols pj..pj+3
    const int pi = tid >> 3;
    const int pj = (tid & 7) << 2;
    float cacc0 = 0.f, cacc1 = 0.f, cacc2 = 0.f, cacc3 = 0.f;

    // gram mapping: rows gi, gi+1 ; cols gj, gj+16  (non-adjacent j pair keeps
    // swizzled LDS reads at <=2-way conflict, which is free on CDNA4)
    const int gi = (tid >> 4) << 1;
    const int gj = tid & 15;

    const int t_load = tid >> 3;   // row t this thread loads
    const int d8 = tid & 7;

    for (int ch = 0; ch < 24; ++ch) {
        const float* src = (ch < H_) ? q : k;
        const int h = (ch < H_) ? ch : ch - H_;
        // ---- stage X = src[b, :, 1+l, h, :] (32x64) into LDS, swizzled ----
        {
            const float* rowp = src + (((size_t)(b * T_ + t_load) * 197 + 1 + l) * DM_) + h * D_;
            float4 v0 = *(const float4*)(rowp + (d8 << 2));
            float4 v1 = *(const float4*)(rowp + (d8 << 2) + 32);
            const int sw = t_load & 15;
            *(float4*)&Xs[(t_load << 6) + (((d8    ) ^ sw) << 2)] = v0;
            *(float4*)&Xs[(t_load << 6) + (((d8 + 8) ^ sw) << 2)] = v1;
        }
        __syncthreads();
        // ---- gram 2x2: G[i][j] = scale * dot64(X[i], X[j]) ----
        {
            float g00 = 0.f, g01 = 0.f, g10 = 0.f, g11 = 0.f;
            const int swa0 = gi & 15, swa1 = (gi + 1) & 15;
            const int swb = gj;   // (gj+16)&15 == gj
            #pragma unroll
            for (int c4 = 0; c4 < 16; ++c4) {
                float4 a0  = *(const float4*)&Xs[( gi     << 6) + ((c4 ^ swa0) << 2)];
                float4 a1  = *(const float4*)&Xs[((gi + 1) << 6) + ((c4 ^ swa1) << 2)];
                float4 b0  = *(const float4*)&Xs[( gj     << 6) + ((c4 ^ swb) << 2)];
                float4 b1v = *(const float4*)&Xs[((gj + 16) << 6) + ((c4 ^ swb) << 2)];
                g00 += a0.x * b0.x  + a0.y * b0.y  + a0.z * b0.z  + a0.w * b0.w;
                g01 += a0.x * b1v.x + a0.y * b1v.y + a0.z * b1v.z + a0.w * b1v.w;
                g10 += a1.x * b0.x  + a1.y * b0.y  + a1.z * b0.z  + a1.w * b0.w;
                g11 += a1.x * b1v.x + a1.y * b1v.y + a1.z * b1v.z + a1.w * b1v.w;
            }
            const float scale = 0.125f;   // 1/sqrt(64)
            As[ gi      * 37 + gj     ] = g00 * scale;
            As[ gi      * 37 + gj + 16] = g01 * scale;
            As[(gi + 1) * 37 + gj     ] = g10 * scale;
            As[(gi + 1) * 37 + gj + 16] = g11 * scale;
        }
        __syncthreads();
        // ---- softmax over cols (k-index) within row pi; in-place on own 4 ----
        {
            float v0 = As[pi * 37 + pj    ];
            float v1 = As[pi * 37 + pj + 1];
            float v2 = As[pi * 37 + pj + 2];
            float v3 = As[pi * 37 + pj + 3];
            float m = fmaxf(fmaxf(v0, v1), fmaxf(v2, v3));
            m = fmaxf(m, __shfl_xor(m, 1, 8));
            m = fmaxf(m, __shfl_xor(m, 2, 8));
            m = fmaxf(m, __shfl_xor(m, 4, 8));
            v0 = __expf(v0 - m); v1 = __expf(v1 - m);
            v2 = __expf(v2 - m); v3 = __expf(v3 - m);
            float s = v0 + v1 + v2 + v3;
            s += __shfl_xor(s, 1, 8);
            s += __shfl_xor(s, 2, 8);
            s += __shfl_xor(s, 4, 8);
            float r = 1.f / s;
            As[pi * 37 + pj    ] = v0 * r;
            As[pi * 37 + pj + 1] = v1 * r;
            As[pi * 37 + pj + 2] = v2 * r;
            As[pi * 37 + pj + 3] = v3 * r;
        }
        __syncthreads();
        // ---- 3x3 conv accumulate (SAME pad, correlation) ----
        {
            float wc[9];
            #pragma unroll
            for (int u = 0; u < 9; ++u) wc[u] = tw[ch * 9 + u];  // uniform -> s_load
            #pragma unroll
            for (int di = 0; di < 3; ++di) {
                int r = pi + di - 1;
                if ((unsigned)r < (unsigned)T_) {
                    float c0 = (pj - 1 >= 0) ? As[r * 37 + pj - 1] : 0.f;
                    float c1 = As[r * 37 + pj    ];
                    float c2 = As[r * 37 + pj + 1];
                    float c3 = As[r * 37 + pj + 2];
                    float c4v = As[r * 37 + pj + 3];
                    float c5 = (pj + 4 < T_) ? As[r * 37 + pj + 4] : 0.f;
                    float w0 = wc[di * 3 + 0], wA = wc[di * 3 + 1], wB = wc[di * 3 + 2];
                    cacc0 += c0 * w0 + c1 * wA + c2 * wB;
                    cacc1 += c1 * w0 + c2 * wA + c3 * wB;
                    cacc2 += c2 * w0 + c3 * wA + c4v * wB;
                    cacc3 += c3 * w0 + c4v * wA + c5 * wB;
                }
            }
        }
        __syncthreads();
    }
    {
        float bb = tbias[0];
        cacc0 += bb; cacc1 += bb; cacc2 += bb; cacc3 += bb;
    }
    // ---- LayerNorm over 1024 values (eps 1e-5) ----
    float mu, rs;
    {
        float s1 = cacc0 + cacc1 + cacc2 + cacc3;
        float s2 = cacc0 * cacc0 + cacc1 * cacc1 + cacc2 * cacc2 + cacc3 * cacc3;
        #pragma unroll
        for (int off = 32; off > 0; off >>= 1) {
            s1 += __shfl_down(s1, off);
            s2 += __shfl_down(s2, off);
        }
        if ((tid & 63) == 0) { redv[tid >> 6] = s1; redv[4 + (tid >> 6)] = s2; }
        __syncthreads();
        float t1 = redv[0] + redv[1] + redv[2] + redv[3];
        float t2 = redv[4] + redv[5] + redv[6] + redv[7];
        mu = t1 * (1.f / 1024.f);
        float var = t2 * (1.f / 1024.f) - mu * mu;
        rs = rsqrtf(var + 1e-5f);
    }
    const int tt0 = (pi << 5) + pj;
    {
        float4 g4 = *(const float4*)&lng[tt0];
        float4 b4 = *(const float4*)&lnb[tt0];
        float4 nv;
        nv.x = (cacc0 - mu) * rs * g4.x + b4.x;
        nv.y = (cacc1 - mu) * rs * g4.y + b4.y;
        nv.z = (cacc2 - mu) * rs * g4.z + b4.z;
        nv.w = (cacc3 - mu) * rs * g4.w + b4.w;
        *(float4*)&nls[tt0] = nv;
    }
    __syncthreads();
    // ---- MLP layer 1: 1024 -> 32 (split the dot over 8 thread-groups) ----
    {
        const int m = tid & 31;
        const int grp = tid >> 5;
        const int base = grp * 128;
        float p = 0.f;
        for (int u = 0; u < 128; ++u)
            p += nls[base + u] * w1[(base + u) * 32 + m];
        scratch[(m << 3) + grp] = p;
    }
    __syncthreads();
    if (tid < 32) {
        float z = b1[tid];
        #pragma unroll
        for (int g = 0; g < 8; ++g) z += scratch[(tid << 3) + g];
        z = 0.5f * z * (1.f + erff(z * 0.70710678118654752f));  // exact GELU
        h1s[tid] = z;
    }
    __syncthreads();
    // ---- MLP layer 2 + residual + store to affbuf[(b*196+l)*1024 + tt] ----
    {
        float4 o4 = *(const float4*)&b2[tt0];
        #pragma unroll
        for (int m = 0; m < 32; ++m) {
            float hm = h1s[m];
            float4 w4 = *(const float4*)&w2[m * 1024 + tt0];
            o4.x += hm * w4.x; o4.y += hm * w4.y;
            o4.z += hm * w4.z; o4.w += hm * w4.w;
        }
        float4 res;
        res.x = cacc0 + o4.x; res.y = cacc1 + o4.y;
        res.z = cacc2 + o4.z; res.w = cacc3 + o4.w;
        float* outp = affbuf + (((size_t)(b * L_ + l)) << 10) + tt0;
        *(float4*)outp = res;
    }
}

// ---------------- Kernel B: p_conv (1024ch 3x3 -> 1), one wg per (b, pixel) --
__global__ __launch_bounds__(256)
void pconv_kernel(const float* __restrict__ affbuf, const float* __restrict__ pw,
                  const float* __restrict__ pb, float* __restrict__ yt)
{
    const int p = blockIdx.x;     // 0..195
    const int b = blockIdx.y;
    const int p1 = p / 14, p2 = p % 14;
    const int tid = threadIdx.x;
    __shared__ float pwS[9216];
    __shared__ float red4[4];
    for (int u = tid << 2; u < 9216; u += 1024)
        *(float4*)&pwS[u] = *(const float4*)&pw[u];
    __syncthreads();
    float acc = 0.f;
    #pragma unroll
    for (int di = 0; di < 3; ++di) {
        const int r = p1 + di - 1;
        if ((unsigned)r >= 14u) continue;
        #pragma unroll
        for (int dj = 0; dj < 3; ++dj) {
            const int c = p2 + dj - 1;
            if ((unsigned)c >= 14u) continue;
            const float* ap = affbuf + (((size_t)(b * 196 + r * 14 + c)) << 10);
            const int wo = di * 3 + dj;
            for (int u = tid; u < 1024; u += 256)
                acc += ap[u] * pwS[u * 9 + wo];
        }
    }
    #pragma unroll
    for (int off = 32; off > 0; off >>= 1) acc += __shfl_down(acc, off);
    if ((tid & 63) == 0) red4[tid >> 6] = acc;
    __syncthreads();
    if (tid == 0) yt[b * 196 + p] = red4[0] + red4[1] + red4[2] + red4[3] + pb[0];
}

// ---------------- Kernel C: spatial path, one wg per (b, t) -----------------
// logits = (syno/sqrt(DM)) @ kk^T ; softmax over l per s ; ps[l] = sum_s p[s,l]
// y_s partial = (1/512) * sum_l ps[l] * vv[l,:]  (atomic over t)
__global__ __launch_bounds__(256)
void spatial_kernel(const float* __restrict__ k, const float* __restrict__ v,
                    const float* __restrict__ syno, float* __restrict__ ys)
{
    const int t = blockIdx.x;   // 0..31
    const int b = blockIdx.y;   // 0..15
    const int tid = threadIdx.x;
    __shared__ float Ls[16 * 208];
    __shared__ float mxs[16], sms[16];
    __shared__ float ps[196];

    const size_t base = ((size_t)(b * T_ + t) * 197 + 1) * DM_;
    const float inv_sqrt_dm = 0.036084391824352f;  // 1/sqrt(768)

    if (tid < 196) {
        const float* kp = k + base + (size_t)tid * DM_;
        float acc[16];
        #pragma unroll
        for (int s = 0; s < 16; ++s) acc[s] = 0.f;
        for (int c0 = 0; c0 < DM_; c0 += 32) {
            float4 chunk[8];
            #pragma unroll
            for (int u = 0; u < 8; ++u) chunk[u] = *(const float4*)(kp + c0 + u * 4);
            #pragma unroll
            for (int s = 0; s < 16; ++s) {
                const float* sp = syno + s * DM_ + c0;   // uniform -> scalar loads
                float a = 0.f;
                #pragma unroll
                for (int u = 0; u < 8; ++u) {
                    a += chunk[u].x * sp[u * 4 + 0] + chunk[u].y * sp[u * 4 + 1]
                       + chunk[u].z * sp[u * 4 + 2] + chunk[u].w * sp[u * 4 + 3];
                }
                acc[s] += a;
            }
        }
        #pragma unroll
        for (int s = 0; s < 16; ++s) Ls[s * 208 + tid] = acc[s] * inv_sqrt_dm;
    }
    __syncthreads();
    // per-s softmax stats: thread (s = tid/16, j = tid%16)
    {
        const int s = tid >> 4, j = tid & 15;
        float m = -1e30f;
        for (int l = j; l < 196; l += 16) m = fmaxf(m, Ls[s * 208 + l]);
        #pragma unroll
        for (int msk = 1; msk < 16; msk <<= 1) m = fmaxf(m, __shfl_xor(m, msk, 16));
        float sum = 0.f;
        for (int l = j; l < 196; l += 16) sum += __expf(Ls[s * 208 + l] - m);
        #pragma unroll
        for (int msk = 1; msk < 16; msk <<= 1) sum += __shfl_xor(sum, msk, 16);
        if (j == 0) { mxs[s] = m; sms[s] = 1.f / sum; }
    }
    __syncthreads();
    if (tid < 196) {
        float p = 0.f;
        #pragma unroll
        for (int s = 0; s < 16; ++s) p += __expf(Ls[s * 208 + tid] - mxs[s]) * sms[s];
        ps[tid] = p;
    }
    __syncthreads();
    if (tid < 192) {
        const float* vp = v + base + tid * 4;
        float4 acc = {0.f, 0.f, 0.f, 0.f};
        for (int l = 0; l < 196; ++l) {
            float p = ps[l];
            float4 vv = *(const float4*)(vp + (size_t)l * DM_);
            acc.x += p * vv.x; acc.y += p * vv.y;
            acc.z += p * vv.z; acc.w += p * vv.w;
        }
        const float f = 1.f / 512.f;   // mean over T*S
        float* o = ys + b * DM_ + tid * 4;
        atomicAdd(o + 0, acc.x * f);
        atomicAdd(o + 1, acc.y * f);
        atomicAdd(o + 2, acc.z * f);
        atomicAdd(o + 3, acc.w * f);
    }
}

extern "C" void kernel_launch(void* const* d_in, const int* in_sizes, int n_in,
                              void* d_out, int out_size, void* d_ws, size_t ws_size,
                              hipStream_t stream) {
    const float* q    = (const float*)d_in[0];
    const float* k    = (const float*)d_in[1];
    const float* v    = (const float*)d_in[2];
    const float* tw   = (const float*)d_in[3];
    const float* tb   = (const float*)d_in[4];
    const float* lng  = (const float*)d_in[5];
    const float* lnb  = (const float*)d_in[6];
    const float* w1   = (const float*)d_in[7];
    const float* b1   = (const float*)d_in[8];
    const float* w2   = (const float*)d_in[9];
    const float* b2   = (const float*)d_in[10];
    const float* pw   = (const float*)d_in[11];
    const float* pb   = (const float*)d_in[12];
    const float* syno = (const float*)d_in[13];

    float* out = (float*)d_out;             // [0,3136) = y_t ; [3136,15424) = y_s
    float* affbuf = (float*)d_ws;           // 16*196*1024 floats = 12.85 MB

    hipMemsetAsync(d_out, 0, (size_t)out_size * sizeof(float), stream);

    temporal_kernel<<<dim3(L_, 16), 256, 0, stream>>>(q, k, tw, tb, lng, lnb,
                                                      w1, b1, w2, b2, affbuf);
    pconv_kernel<<<dim3(L_, 16), 256, 0, stream>>>(affbuf, pw, pb, out);
    spatial_kernel<<<dim3(T_, 16), 256, 0, stream>>>(k, v, syno, out + 3136);
}